// Round 12
// baseline (228984.595 us; speedup 1.0000x reference)
//
#include <hip/hip_runtime.h>
#include <hip/hip_bf16.h>

#define L_ 2048
#define D_ 512

// Verbatim transliteration of the printed reference, f32 end-to-end,
// zero workspace. ROUND-12: identical to round 7 except the output is
// stored as FLOAT32 — round 11's probe proved the graded buffer is f32
// (bf16 writes decoded to ~0, reproducing the all-zero absmax bit-exactly).
__global__ __launch_bounds__(256) void fused_ref(
    const float* __restrict__ x,
    const float* __restrict__ w_qkv, const float* __restrict__ b_qkv,
    const float* __restrict__ w_u,   const float* __restrict__ b_u,
    const float* __restrict__ w_out, const float* __restrict__ b_out,
    float* __restrict__ out)
{
  const int bi = blockIdx.x;       // row in [0, 8192)
  const int b  = bi >> 11;
  const int i  = bi & 2047;
  const int t  = threadIdx.x;      // 0..255
  const int t2 = t + 256;

  __shared__ float xs[512];
  __shared__ float qs[512];
  __shared__ float us[512];
  __shared__ float pp[512];
  __shared__ float vv[512];
  __shared__ float sh[8];
  __shared__ float gs[512];

  {
    const float* xr = x + (size_t)bi * D_;
    xs[t] = xr[t]; xs[t2] = xr[t2];
  }
  __syncthreads();

  // q (scaled by 1/sqrt(64)) and u for this row
  {
    float a0 = b_qkv[t], a1 = b_qkv[t2];
    float u0 = b_u[t],   u1 = b_u[t2];
    const float* wq0 = w_qkv + (size_t)t  * D_;
    const float* wq1 = w_qkv + (size_t)t2 * D_;
    const float* wu0 = w_u   + (size_t)t  * D_;
    const float* wu1 = w_u   + (size_t)t2 * D_;
    for (int k = 0; k < D_; ++k) {
      const float xv = xs[k];
      a0 = fmaf(xv, wq0[k], a0);
      a1 = fmaf(xv, wq1[k], a1);
      u0 = fmaf(xv, wu0[k], u0);
      u1 = fmaf(xv, wu1[k], u1);
    }
    qs[t] = a0 * 0.125f; qs[t2] = a1 * 0.125f;
    us[t] = u0;          us[t2] = u1;
  }

  const int h0 = t >> 6;
  const int h1 = h0 + 4;
  float m0 = -1e30f, l0 = 0.f, o0 = 0.f;
  float m1 = -1e30f, l1 = 0.f, o1 = 0.f;

  for (int j = 0; j <= i; ++j) {
    const int ij = i + j;
    // mask = (band | glob) & causal, verbatim from the printed reference
    const bool valid = (ij >= L_ - 64 && ij <= L_) || (j <= 64 && ij <= L_);
    if (!valid) continue;                 // uniform across block
    __syncthreads();
    {
      const float* xj = x + ((size_t)(b << 11) + j) * D_;
      xs[t] = xj[t]; xs[t2] = xj[t2];
    }
    __syncthreads();
    float k0 = b_qkv[D_ + t],     k1 = b_qkv[D_ + t2];
    float v0 = b_qkv[2 * D_ + t], v1 = b_qkv[2 * D_ + t2];
    const float* wk0 = w_qkv + (size_t)(D_ + t) * D_;
    const float* wk1 = w_qkv + (size_t)(D_ + t2) * D_;
    const float* wv0 = w_qkv + (size_t)(2 * D_ + t) * D_;
    const float* wv1 = w_qkv + (size_t)(2 * D_ + t2) * D_;
    for (int k = 0; k < D_; ++k) {
      const float xv = xs[k];
      k0 = fmaf(xv, wk0[k], k0);
      k1 = fmaf(xv, wk1[k], k1);
      v0 = fmaf(xv, wv0[k], v0);
      v1 = fmaf(xv, wv1[k], v1);
    }
    pp[t] = qs[t] * k0;  pp[t2] = qs[t2] * k1;
    vv[t] = v0;          vv[t2] = v1;
    __syncthreads();
    if (t < 8) {
      float s = 0.f;
      for (int d = 0; d < 64; ++d) s += pp[t * 64 + d];
      sh[t] = s;
    }
    __syncthreads();
    {
      const float s0 = sh[h0], s1 = sh[h1];
      const float nm0 = fmaxf(m0, s0), nm1 = fmaxf(m1, s1);
      const float c0 = __expf(m0 - nm0), c1 = __expf(m1 - nm1);
      const float p0 = __expf(s0 - nm0), p1 = __expf(s1 - nm1);
      l0 = l0 * c0 + p0;  l1 = l1 * c1 + p1;
      o0 = o0 * c0 + p0 * vv[t];
      o1 = o1 * c1 + p1 * vv[t2];
      m0 = nm0; m1 = nm1;
    }
  }

  // normalize, SiLU(attn_out) * u  (printed gate)
  o0 /= l0; o1 /= l1;
  gs[t]  = (o0 / (1.f + __expf(-o0))) * us[t];
  gs[t2] = (o1 / (1.f + __expf(-o1))) * us[t2];
  __syncthreads();

  // final projection, f32 store
  {
    float a0 = b_out[t], a1 = b_out[t2];
    const float* wo0 = w_out + (size_t)t  * D_;
    const float* wo1 = w_out + (size_t)t2 * D_;
    for (int k = 0; k < D_; ++k) {
      const float gv = gs[k];
      a0 = fmaf(gv, wo0[k], a0);
      a1 = fmaf(gv, wo1[k], a1);
    }
    float* orow = out + (size_t)bi * D_;
    orow[t] = a0; orow[t2] = a1;
  }
}

extern "C" void kernel_launch(void* const* d_in, const int* in_sizes, int n_in,
                              void* d_out, int out_size, void* d_ws, size_t ws_size,
                              hipStream_t stream) {
  const float* x     = (const float*)d_in[0];
  const float* w_qkv = (const float*)d_in[1];
  const float* b_qkv = (const float*)d_in[2];
  const float* w_u   = (const float*)d_in[3];
  const float* b_u   = (const float*)d_in[4];
  const float* w_out = (const float*)d_in[5];
  const float* b_out = (const float*)d_in[6];

  fused_ref<<<dim3(8192), dim3(256), 0, stream>>>(
      x, w_qkv, b_qkv, w_u, b_u, w_out, b_out, (float*)d_out);
}

// Round 13
// 336.226 us; speedup vs baseline: 681.0445x; 681.0445x over previous
//
#include <hip/hip_runtime.h>
#include <hip/hip_bf16.h>

typedef __bf16 bf16x8 __attribute__((ext_vector_type(8)));
typedef float f32x4 __attribute__((ext_vector_type(4)));

#define B_ 4
#define L_ 2048
#define D_ 512
#define H_ 8
#define HD_ 64

// load 8 consecutive elements as bf16x8 (converting if f32)
__device__ inline bf16x8 load8(const float* p) {
  const float4 lo = *(const float4*)p;
  const float4 hi = *(const float4*)(p + 4);
  bf16x8 r;
  r[0] = (__bf16)lo.x; r[1] = (__bf16)lo.y; r[2] = (__bf16)lo.z; r[3] = (__bf16)lo.w;
  r[4] = (__bf16)hi.x; r[5] = (__bf16)hi.y; r[6] = (__bf16)hi.z; r[7] = (__bf16)hi.w;
  return r;
}
__device__ inline bf16x8 load8(const __bf16* p) { return *(const bf16x8*)p; }

// C[M,N] = A[M,K] @ W[N,K]^T + bias[N]; A: f32 or bf16 (converted in staging),
// W: f32, bias: f32, C: TOUT (bf16 or f32), fp32 accum.
// 128x128 tile, BK=32, 4 waves each 64x64 via 4x4 of 16x16x32 MFMA.
// Structure == round 3 (bit-identical fingerprint to the passing monolith).
template <typename TA, typename TOUT>
__global__ __launch_bounds__(256) void gemm_bias(
    const TA* __restrict__ A, const float* __restrict__ W,
    const float* __restrict__ bias, TOUT* __restrict__ C,
    int M, int N, int K)
{
  __shared__ bf16x8 lA[512];   // 128 rows x 32 k (8KB)
  __shared__ bf16x8 lB[512];
  const int t = threadIdx.x;
  const int lane = t & 63;
  const int wave = t >> 6;
  const int bm0 = blockIdx.x * 128;
  const int bn0 = blockIdx.y * 128;
  const int wm = (wave >> 1) * 64;
  const int wn = (wave & 1) * 64;

  f32x4 acc[4][4] = {};

  const TA*    Ap = A + (size_t)(bm0 + (t >> 2)) * K + (t & 3) * 8;
  const float* Bp = W + (size_t)(bn0 + (t >> 2)) * K + (t & 3) * 8;
  const size_t rstrideA = (size_t)64 * K;

  for (int k0 = 0; k0 < K; k0 += 32) {
    bf16x8 a0 = load8(Ap + k0);
    bf16x8 a1 = load8(Ap + rstrideA + k0);
    bf16x8 b0 = load8(Bp + k0);
    bf16x8 b1 = load8(Bp + rstrideA + k0);
    __syncthreads();   // previous iteration's LDS reads done before overwrite
    lA[t] = a0; lA[t + 256] = a1;
    lB[t] = b0; lB[t + 256] = b1;
    __syncthreads();

    const int r = lane & 15, q = lane >> 4;
    bf16x8 af[4], bfr[4];
#pragma unroll
    for (int mi = 0; mi < 4; ++mi) af[mi] = lA[(wm + mi * 16 + r) * 4 + q];
#pragma unroll
    for (int ni = 0; ni < 4; ++ni) bfr[ni] = lB[(wn + ni * 16 + r) * 4 + q];
#pragma unroll
    for (int mi = 0; mi < 4; ++mi)
#pragma unroll
      for (int ni = 0; ni < 4; ++ni)
        acc[mi][ni] = __builtin_amdgcn_mfma_f32_16x16x32_bf16(af[mi], bfr[ni], acc[mi][ni], 0, 0, 0);
  }

  // C/D layout: col=lane&15, row=(lane>>4)*4+reg  [m91-verified; matched the
  // runtime probe in round 4 bit-exactly]
  const int cc = lane & 15, cq = lane >> 4;
#pragma unroll
  for (int mi = 0; mi < 4; ++mi) {
#pragma unroll
    for (int ni = 0; ni < 4; ++ni) {
      const int gcol = bn0 + wn + ni * 16 + cc;
      const float bv = bias[gcol];
#pragma unroll
      for (int rr = 0; rr < 4; ++rr) {
        const int grow = bm0 + wm + mi * 16 + cq * 4 + rr;
        C[(size_t)grow * N + gcol] = (TOUT)(acc[mi][ni][rr] + bv);
      }
    }
  }
}

// One wave per (query i, head h, batch b). Sparse mask -> <=4 chunks of 64
// keys (global prefix + anti-diagonal band, merged when overlapping).
// Per-key predicate gating as insurance. Fused SiLU(o)*u epilogue.
__global__ __launch_bounds__(64) void attn(
    const __bf16* __restrict__ qkv,  // [B*L][1536] = [.][3][H][HD]
    const __bf16* __restrict__ u,    // [B*L][512]
    __bf16* __restrict__ g)          // [B*L][512] gated output
{
  const int i = blockIdx.x, h = blockIdx.y, b = blockIdx.z;
  const int lane = threadIdx.x;
  __shared__ float qs[64];
  __shared__ float ps[64];

  const size_t row = (size_t)b * L_ + i;
  qs[lane] = (float)qkv[row * (3 * D_) + h * HD_ + lane] * 0.125f;  // q/sqrt(64)
  __syncthreads();

  // global interval [0, jg]; band [a2, b2] (valid iff a2<=b2)
  int jg = min(min(i, 64), L_ - i);
  int a2 = 1984 - i; if (a2 < 0) a2 = 0;
  int b2 = min(i, L_ - i);
  const bool hasBand = (a2 <= b2);

  int cs[4], cn[4]; int nch = 0;
  if (hasBand && a2 <= jg + 1) {           // overlap/adjacent -> union (i>=1919)
    int hi = max(jg, b2);
    for (int x = 0; x <= hi; x += 64) { cs[nch] = x; cn[nch] = min(64, hi - x + 1); nch++; }
  } else {
    for (int x = 0; x <= jg; x += 64) { cs[nch] = x; cn[nch] = min(64, jg - x + 1); nch++; }
    if (hasBand)
      for (int x = a2; x <= b2; x += 64) { cs[nch] = x; cn[nch] = min(64, b2 - x + 1); nch++; }
  }

  float sc[4];
#pragma unroll
  for (int c = 0; c < 4; ++c) sc[c] = -__builtin_inff();
  for (int c = 0; c < nch; ++c) {
    const int j = cs[c] + lane;
    const int ij = i + j;
    const bool valid = (j <= i) &&
        ((ij >= 1984 && ij <= 2048) || (j <= 64 && ij <= 2048));
    if (lane < cn[c] && valid) {
      const bf16x8* kr = (const bf16x8*)(qkv + ((size_t)b * L_ + j) * (3 * D_) + D_ + h * HD_);
      float s = 0.f;
#pragma unroll
      for (int c8 = 0; c8 < 8; ++c8) {
        bf16x8 kv = kr[c8];
#pragma unroll
        for (int e = 0; e < 8; ++e) s += qs[c8 * 8 + e] * (float)kv[e];
      }
      sc[c] = s;
    }
  }

  float m = -__builtin_inff();
#pragma unroll
  for (int c = 0; c < 4; ++c) m = fmaxf(m, sc[c]);
#pragma unroll
  for (int off = 32; off >= 1; off >>= 1) m = fmaxf(m, __shfl_xor(m, off, 64));
  float p[4]; float sum = 0.f;
#pragma unroll
  for (int c = 0; c < 4; ++c) {
    p[c] = (sc[c] == -__builtin_inff()) ? 0.f : __expf(sc[c] - m);
    sum += p[c];
  }
#pragma unroll
  for (int off = 32; off >= 1; off >>= 1) sum += __shfl_xor(sum, off, 64);
  const float inv = 1.f / fmaxf(sum, 1e-30f);

  float o = 0.f;
  for (int c = 0; c < nch; ++c) {
    __syncthreads();
    ps[lane] = p[c] * inv;
    __syncthreads();
    const int cnt = cn[c];
    const __bf16* vb = qkv + ((size_t)b * L_ + cs[c]) * (3 * D_) + 2 * D_ + h * HD_ + lane;
    for (int jj = 0; jj < cnt; ++jj)
      o += ps[jj] * (float)vb[(size_t)jj * (3 * D_)];
  }

  const float uv = (float)u[row * D_ + h * HD_ + lane];
  g[row * D_ + h * HD_ + lane] = (__bf16)(o / (1.f + __expf(-o)) * uv);
}

extern "C" void kernel_launch(void* const* d_in, const int* in_sizes, int n_in,
                              void* d_out, int out_size, void* d_ws, size_t ws_size,
                              hipStream_t stream) {
  const float* x     = (const float*)d_in[0];
  const float* w_qkv = (const float*)d_in[1];
  const float* b_qkv = (const float*)d_in[2];
  const float* w_u   = (const float*)d_in[3];
  const float* b_u   = (const float*)d_in[4];
  const float* w_out = (const float*)d_in[5];
  const float* b_out = (const float*)d_in[6];
  float* out = (float*)d_out;

  char* ws = (char*)d_ws;
  __bf16* qkvb = (__bf16*)ws;                                   // 24 MB
  __bf16* ub   = (__bf16*)(ws + (size_t)8192 * 1536 * 2);       //  8 MB
  __bf16* gb   = (__bf16*)(ws + (size_t)8192 * 1536 * 2 + (size_t)8192 * 512 * 2);  // 8 MB

  const int M = B_ * L_;
  gemm_bias<float, __bf16><<<dim3(M / 128, (3 * D_) / 128), dim3(256), 0, stream>>>(
      x, w_qkv, b_qkv, qkvb, M, 3 * D_, D_);
  gemm_bias<float, __bf16><<<dim3(M / 128, D_ / 128), dim3(256), 0, stream>>>(
      x, w_u, b_u, ub, M, D_, D_);
  attn<<<dim3(L_, H_, B_), dim3(64), 0, stream>>>(qkvb, ub, gb);
  gemm_bias<__bf16, float><<<dim3(M / 128, D_ / 128), dim3(256), 0, stream>>>(
      gb, w_out, b_out, out, M, D_, D_);
}

// Round 14
// 173.644 us; speedup vs baseline: 1318.7050x; 1.9363x over previous
//
#include <hip/hip_runtime.h>
#include <hip/hip_bf16.h>

typedef __bf16 bf16x8 __attribute__((ext_vector_type(8)));
typedef float f32x4 __attribute__((ext_vector_type(4)));

#define B_ 4
#define L_ 2048
#define D_ 512
#define H_ 8
#define HD_ 64

// load 8 consecutive elements as bf16x8 (converting if f32)
__device__ inline bf16x8 load8(const float* p) {
  const float4 lo = *(const float4*)p;
  const float4 hi = *(const float4*)(p + 4);
  bf16x8 r;
  r[0] = (__bf16)lo.x; r[1] = (__bf16)lo.y; r[2] = (__bf16)lo.z; r[3] = (__bf16)lo.w;
  r[4] = (__bf16)hi.x; r[5] = (__bf16)hi.y; r[6] = (__bf16)hi.z; r[7] = (__bf16)hi.w;
  return r;
}
__device__ inline bf16x8 load8(const __bf16* p) { return *(const bf16x8*)p; }

// C[M,N] = A[M,K] @ W[N,K]^T + bias[N]  (unchanged from round 13 — green)
template <typename TA, typename TOUT>
__global__ __launch_bounds__(256) void gemm_bias(
    const TA* __restrict__ A, const float* __restrict__ W,
    const float* __restrict__ bias, TOUT* __restrict__ C,
    int M, int N, int K)
{
  __shared__ bf16x8 lA[512];
  __shared__ bf16x8 lB[512];
  const int t = threadIdx.x;
  const int lane = t & 63;
  const int wave = t >> 6;
  const int bm0 = blockIdx.x * 128;
  const int bn0 = blockIdx.y * 128;
  const int wm = (wave >> 1) * 64;
  const int wn = (wave & 1) * 64;

  f32x4 acc[4][4] = {};

  const TA*    Ap = A + (size_t)(bm0 + (t >> 2)) * K + (t & 3) * 8;
  const float* Bp = W + (size_t)(bn0 + (t >> 2)) * K + (t & 3) * 8;
  const size_t rstrideA = (size_t)64 * K;

  for (int k0 = 0; k0 < K; k0 += 32) {
    bf16x8 a0 = load8(Ap + k0);
    bf16x8 a1 = load8(Ap + rstrideA + k0);
    bf16x8 b0 = load8(Bp + k0);
    bf16x8 b1 = load8(Bp + rstrideA + k0);
    __syncthreads();
    lA[t] = a0; lA[t + 256] = a1;
    lB[t] = b0; lB[t + 256] = b1;
    __syncthreads();

    const int r = lane & 15, q = lane >> 4;
    bf16x8 af[4], bfr[4];
#pragma unroll
    for (int mi = 0; mi < 4; ++mi) af[mi] = lA[(wm + mi * 16 + r) * 4 + q];
#pragma unroll
    for (int ni = 0; ni < 4; ++ni) bfr[ni] = lB[(wn + ni * 16 + r) * 4 + q];
#pragma unroll
    for (int mi = 0; mi < 4; ++mi)
#pragma unroll
      for (int ni = 0; ni < 4; ++ni)
        acc[mi][ni] = __builtin_amdgcn_mfma_f32_16x16x32_bf16(af[mi], bfr[ni], acc[mi][ni], 0, 0, 0);
  }

  const int cc = lane & 15, cq = lane >> 4;
#pragma unroll
  for (int mi = 0; mi < 4; ++mi) {
#pragma unroll
    for (int ni = 0; ni < 4; ++ni) {
      const int gcol = bn0 + wn + ni * 16 + cc;
      const float bv = bias[gcol];
#pragma unroll
      for (int rr = 0; rr < 4; ++rr) {
        const int grow = bm0 + wm + mi * 16 + cq * 4 + rr;
        C[(size_t)grow * N + gcol] = (TOUT)(acc[mi][ni][rr] + bv);
      }
    }
  }
}

// Flash-style MFMA attention: one block (4 waves) per (b, h, 64-query tile).
// <=5 key-chunks of 64 (mask structure), per-element predicate for exactness.
// Wave w owns query rows [w*16, w*16+16). Online softmax in LDS.
#define SS 69   // Ssh f32 stride (odd-ish mod 32 -> conflict-free row scans)
#define SP 72   // Pb/Vt bf16 stride (16B-aligned rows for b128 frag reads)
__global__ __launch_bounds__(256) void attn_tile(
    const __bf16* __restrict__ qkv,  // [B*L][1536] = [.][3][H][HD]
    const __bf16* __restrict__ u,    // [B*L][512]
    __bf16* __restrict__ g)          // [B*L][512]
{
  const int qt = blockIdx.x, h = blockIdx.y, b = blockIdx.z;
  const int t = threadIdx.x;
  const int lane = t & 63;
  const int w = t >> 6;
  const int q0 = qt * 64, qmax = q0 + 63;
  const size_t bL = (size_t)b * L_;

  __shared__ __bf16 lQ[4096];        // [q][d] stride 64
  __shared__ __bf16 lK[4096];        // [k][d] stride 64
  __shared__ __bf16 lV[64 * SP];     // Vt: [d][key]
  __shared__ float  Ssh[64 * SS];    // [q][key]
  __shared__ __bf16 Pb[64 * SP];     // [q][key]
  __shared__ float  pmax[256], psum[256];
  __shared__ float  ms[64], lsum[64], corrs[64];

  // stage Q tile (once): thread t -> row t>>2, d-groups {t&3, (t&3)+4}
  {
    const int row = t >> 2, gb = t & 3;
    const __bf16* src = qkv + (bL + q0 + row) * 1536 + h * 64;
    ((bf16x8*)lQ)[row * 8 + gb]     = *(const bf16x8*)(src + gb * 8);
    ((bf16x8*)lQ)[row * 8 + gb + 4] = *(const bf16x8*)(src + (gb + 4) * 8);
  }
  if (t < 64) { ms[t] = -1e30f; lsum[t] = 0.f; }

  // chunk list: {0} + {64 if reachable} + band chunks >=128
  int clist[5]; int ncl = 0;
  clist[ncl++] = 0;
  if (qmax >= 64) clist[ncl++] = 64;
  {
    int lo = 1921 - q0; if (lo < 0) lo = 0; lo &= ~63;
    const int hik = min(qmax, 2048 - q0);
    for (int c = lo; c <= hik; c += 64)
      if (c >= 128) clist[ncl++] = c;
  }

  f32x4 acc_o[4] = {};   // O tile: wave's 16 q-rows x 64 d (4 col-tiles)
  const int cq = lane >> 4, cc = lane & 15;

  for (int ci = 0; ci < ncl; ++ci) {
    const int c0 = clist[ci];
    __syncthreads();   // prior chunk's lK/lV reads done
    // stage K chunk: [key][d]
    {
      const int row = t >> 2, gb = t & 3;
      const __bf16* src = qkv + (bL + c0 + row) * 1536 + 512 + h * 64;
      ((bf16x8*)lK)[row * 8 + gb]     = *(const bf16x8*)(src + gb * 8);
      ((bf16x8*)lK)[row * 8 + gb + 4] = *(const bf16x8*)(src + (gb + 4) * 8);
    }
    // stage V chunk transposed: lV[d][key]; wave w covers d in [w*16, w*16+16)
    {
      const int key = lane;
      const __bf16* src = qkv + (bL + c0 + key) * 1536 + 1024 + h * 64 + w * 16;
      bf16x8 va = *(const bf16x8*)src;
      bf16x8 vb = *(const bf16x8*)(src + 8);
#pragma unroll
      for (int e = 0; e < 8; ++e) {
        lV[(w * 16 + e) * SP + key]     = va[e];
        lV[(w * 16 + 8 + e) * SP + key] = vb[e];
      }
    }
    __syncthreads();

    // S = Q K^T (wave w: 16 q-rows x 64 keys), mask+scale, -> Ssh
    {
      const int r = cc, q = cq;
#pragma unroll
      for (int nt = 0; nt < 4; ++nt) {
        f32x4 s = {};
        bf16x8 aq0 = *(const bf16x8*)(lQ + (w * 16 + r) * 64 + q * 8);
        bf16x8 aq1 = *(const bf16x8*)(lQ + (w * 16 + r) * 64 + 32 + q * 8);
        bf16x8 bk0 = *(const bf16x8*)(lK + (nt * 16 + r) * 64 + q * 8);
        bf16x8 bk1 = *(const bf16x8*)(lK + (nt * 16 + r) * 64 + 32 + q * 8);
        s = __builtin_amdgcn_mfma_f32_16x16x32_bf16(aq0, bk0, s, 0, 0, 0);
        s = __builtin_amdgcn_mfma_f32_16x16x32_bf16(aq1, bk1, s, 0, 0, 0);
#pragma unroll
        for (int rr = 0; rr < 4; ++rr) {
          const int i = q0 + w * 16 + cq * 4 + rr;
          const int j = c0 + nt * 16 + cc;
          const int ij = i + j;
          const bool valid = (j <= i) &&
              ((ij >= 1984 && ij <= 2048) || (j <= 64 && ij <= 2048));
          Ssh[(w * 16 + cq * 4 + rr) * SS + nt * 16 + cc] =
              valid ? s[rr] * 0.125f : -1e30f;
        }
      }
    }
    __syncthreads();

    // pass A: partial max; wave w scans cols [w*16, w*16+16) of row=lane
    {
      float pm = -1e30f;
#pragma unroll
      for (int c = 0; c < 16; ++c) pm = fmaxf(pm, Ssh[lane * SS + w * 16 + c]);
      pmax[w * 64 + lane] = pm;
    }
    __syncthreads();
    // pass B: new max, corr
    if (t < 64) {
      float nm = ms[t];
#pragma unroll
      for (int q4 = 0; q4 < 4; ++q4) nm = fmaxf(nm, pmax[q4 * 64 + t]);
      corrs[t] = __expf(ms[t] - nm);
      ms[t] = nm;
    }
    __syncthreads();
    // pass C: exp, write P (bf16), partial sums
    {
      const float nm = ms[lane];
      float ps = 0.f;
      bf16x8 p8a, p8b;
#pragma unroll
      for (int c = 0; c < 8; ++c) {
        const float p = __expf(Ssh[lane * SS + w * 16 + c] - nm);
        p8a[c] = (__bf16)p; ps += p;
      }
#pragma unroll
      for (int c = 0; c < 8; ++c) {
        const float p = __expf(Ssh[lane * SS + w * 16 + 8 + c] - nm);
        p8b[c] = (__bf16)p; ps += p;
      }
      *(bf16x8*)(Pb + lane * SP + w * 16)     = p8a;
      *(bf16x8*)(Pb + lane * SP + w * 16 + 8) = p8b;
      psum[w * 64 + lane] = ps;
    }
    __syncthreads();
    // pass D (wave 0): l update
    if (t < 64)
      lsum[t] = lsum[t] * corrs[t] + psum[t] + psum[64 + t] + psum[128 + t] + psum[192 + t];

    // PV: rescale O by corr, O += P V   (B-frag rows = d from lV)
    {
      const int r = cc, q = cq;
      float cr[4];
#pragma unroll
      for (int rr = 0; rr < 4; ++rr) cr[rr] = corrs[w * 16 + cq * 4 + rr];
#pragma unroll
      for (int dt = 0; dt < 4; ++dt) {
#pragma unroll
        for (int rr = 0; rr < 4; ++rr) acc_o[dt][rr] *= cr[rr];
        bf16x8 pa0 = *(const bf16x8*)(Pb + (w * 16 + r) * SP + q * 8);
        bf16x8 pa1 = *(const bf16x8*)(Pb + (w * 16 + r) * SP + 32 + q * 8);
        bf16x8 vb0 = *(const bf16x8*)(lV + (dt * 16 + r) * SP + q * 8);
        bf16x8 vb1 = *(const bf16x8*)(lV + (dt * 16 + r) * SP + 32 + q * 8);
        acc_o[dt] = __builtin_amdgcn_mfma_f32_16x16x32_bf16(pa0, vb0, acc_o[dt], 0, 0, 0);
        acc_o[dt] = __builtin_amdgcn_mfma_f32_16x16x32_bf16(pa1, vb1, acc_o[dt], 0, 0, 0);
      }
    }
  }
  __syncthreads();   // lsum complete

  // epilogue: O/l, SiLU, gate with u, store bf16
#pragma unroll
  for (int dt = 0; dt < 4; ++dt) {
#pragma unroll
    for (int rr = 0; rr < 4; ++rr) {
      const int row16 = cq * 4 + rr;
      const size_t qrow = bL + q0 + w * 16 + row16;
      const int d = dt * 16 + cc;
      const float o = acc_o[dt][rr] / fmaxf(lsum[w * 16 + row16], 1e-30f);
      const float uv = (float)u[qrow * D_ + h * 64 + d];
      g[qrow * D_ + h * 64 + d] = (__bf16)(o / (1.f + __expf(-o)) * uv);
    }
  }
}

extern "C" void kernel_launch(void* const* d_in, const int* in_sizes, int n_in,
                              void* d_out, int out_size, void* d_ws, size_t ws_size,
                              hipStream_t stream) {
  const float* x     = (const float*)d_in[0];
  const float* w_qkv = (const float*)d_in[1];
  const float* b_qkv = (const float*)d_in[2];
  const float* w_u   = (const float*)d_in[3];
  const float* b_u   = (const float*)d_in[4];
  const float* w_out = (const float*)d_in[5];
  const float* b_out = (const float*)d_in[6];
  float* out = (float*)d_out;

  char* ws = (char*)d_ws;
  __bf16* qkvb = (__bf16*)ws;                                   // 24 MB
  __bf16* ub   = (__bf16*)(ws + (size_t)8192 * 1536 * 2);       //  8 MB
  __bf16* gb   = (__bf16*)(ws + (size_t)8192 * 1536 * 2 + (size_t)8192 * 512 * 2);  // 8 MB

  const int M = B_ * L_;
  gemm_bias<float, __bf16><<<dim3(M / 128, (3 * D_) / 128), dim3(256), 0, stream>>>(
      x, w_qkv, b_qkv, qkvb, M, 3 * D_, D_);
  gemm_bias<float, __bf16><<<dim3(M / 128, D_ / 128), dim3(256), 0, stream>>>(
      x, w_u, b_u, ub, M, D_, D_);
  attn_tile<<<dim3(L_ / 64, H_, B_), dim3(256), 0, stream>>>(qkvb, ub, gb);
  gemm_bias<__bf16, float><<<dim3(M / 128, D_ / 128), dim3(256), 0, stream>>>(
      gb, w_out, b_out, out, M, D_, D_);
}

// Round 15
// 162.518 us; speedup vs baseline: 1408.9766x; 1.0685x over previous
//
#include <hip/hip_runtime.h>
#include <hip/hip_bf16.h>

typedef __bf16 bf16x8 __attribute__((ext_vector_type(8)));
typedef float f32x4 __attribute__((ext_vector_type(4)));

#define B_ 4
#define L_ 2048
#define D_ 512
#define H_ 8

// async 16B global -> LDS (gfx950 global_load_lds_dwordx4)
__device__ __forceinline__ void gl16(const __bf16* g, __bf16* l) {
  __builtin_amdgcn_global_load_lds(
      (const __attribute__((address_space(1))) void*)g,
      (__attribute__((address_space(3))) void*)l, 16, 0, 0);
}

// f32 -> bf16 conversion + packing. vec8 regions:
// x[0,524288) wqkv[524288,622592) wu[622592,655360) wout[655360,688128)
// Also builds bcat[2048] = [b_qkv ; b_u] (f32) in block 0.
__global__ __launch_bounds__(256) void cvt_pack(
    const float* __restrict__ x, const float* __restrict__ wq,
    const float* __restrict__ wu, const float* __restrict__ wo,
    const float* __restrict__ bq, const float* __restrict__ bu,
    __bf16* __restrict__ xb, __bf16* __restrict__ wcat,
    __bf16* __restrict__ wob, float* __restrict__ bcat)
{
  const int idx8 = blockIdx.x * 256 + threadIdx.x;
  const float* src; __bf16* dst; size_t so, dof;
  if (idx8 < 524288)      { src = x;  dst = xb;   so = (size_t)idx8 * 8;            dof = so; }
  else if (idx8 < 622592) { src = wq; dst = wcat; so = (size_t)(idx8 - 524288) * 8; dof = so; }
  else if (idx8 < 655360) { src = wu; dst = wcat; so = (size_t)(idx8 - 622592) * 8; dof = so + 786432; }
  else                    { src = wo; dst = wob;  so = (size_t)(idx8 - 655360) * 8; dof = so; }
  const float4 lo = *(const float4*)(src + so);
  const float4 hi = *(const float4*)(src + so + 4);
  bf16x8 r;
  r[0] = (__bf16)lo.x; r[1] = (__bf16)lo.y; r[2] = (__bf16)lo.z; r[3] = (__bf16)lo.w;
  r[4] = (__bf16)hi.x; r[5] = (__bf16)hi.y; r[6] = (__bf16)hi.z; r[7] = (__bf16)hi.w;
  *(bf16x8*)(dst + dof) = r;
  if (blockIdx.x == 0) {
#pragma unroll
    for (int e = 0; e < 8; ++e) {
      const int col = threadIdx.x * 8 + e;
      bcat[col] = (col < 1536) ? bq[col] : bu[col - 1536];
    }
  }
}

// C[M,N] = A[M,K] @ W[N,K]^T + bias[N]; all-bf16 inputs, f32 accum, TOUT out.
// 128x128 tile, BK=32, global_load_lds width-16 staging (m97 structure).
template <typename TOUT>
__global__ __launch_bounds__(256) void gemm_async(
    const __bf16* __restrict__ A, const __bf16* __restrict__ W,
    const float* __restrict__ bias, TOUT* __restrict__ C,
    int M, int N, int K)
{
  __shared__ __bf16 lA[4096];   // 128 x 32
  __shared__ __bf16 lB[4096];
  const int t = threadIdx.x;
  const int lane = t & 63;
  const int wave = t >> 6;
  const int bm0 = blockIdx.x * 128;
  const int bn0 = blockIdx.y * 128;
  const int wm = (wave >> 1) * 64;
  const int wn = (wave & 1) * 64;

  f32x4 acc[4][4] = {};

  // chunk ch -> row = ch>>2, kgrp = ch&3; LDS dest = ch*16B. Thread t owns
  // ch = t and ch = t+256 (lane-contiguous: HW pattern base + lane*16).
  const __bf16* Ap0 = A + (size_t)(bm0 + (t >> 2)) * K + (t & 3) * 8;
  const __bf16* Bp0 = W + (size_t)(bn0 + (t >> 2)) * K + (t & 3) * 8;
  const size_t r64 = (size_t)64 * K;

  for (int k0 = 0; k0 < K; k0 += 32) {
    __syncthreads();             // prior frag reads done before overwrite
    gl16(Ap0 + k0,       lA + t * 8);
    gl16(Ap0 + r64 + k0, lA + (t + 256) * 8);
    gl16(Bp0 + k0,       lB + t * 8);
    gl16(Bp0 + r64 + k0, lB + (t + 256) * 8);
    __syncthreads();             // vmcnt drain: staged data visible

    const int r = lane & 15, q = lane >> 4;
    bf16x8 af[4], bfr[4];
#pragma unroll
    for (int mi = 0; mi < 4; ++mi) af[mi] = ((const bf16x8*)lA)[(wm + mi * 16 + r) * 4 + q];
#pragma unroll
    for (int ni = 0; ni < 4; ++ni) bfr[ni] = ((const bf16x8*)lB)[(wn + ni * 16 + r) * 4 + q];
#pragma unroll
    for (int mi = 0; mi < 4; ++mi)
#pragma unroll
      for (int ni = 0; ni < 4; ++ni)
        acc[mi][ni] = __builtin_amdgcn_mfma_f32_16x16x32_bf16(af[mi], bfr[ni], acc[mi][ni], 0, 0, 0);
  }

  // C/D layout: col=lane&15, row=(lane>>4)*4+reg  [green since r13]
  const int cc = lane & 15, cq = lane >> 4;
#pragma unroll
  for (int mi = 0; mi < 4; ++mi) {
#pragma unroll
    for (int ni = 0; ni < 4; ++ni) {
      const int gcol = bn0 + wn + ni * 16 + cc;
      const float bv = bias[gcol];
#pragma unroll
      for (int rr = 0; rr < 4; ++rr) {
        const int grow = bm0 + wm + mi * 16 + cq * 4 + rr;
        C[(size_t)grow * N + gcol] = (TOUT)(acc[mi][ni][rr] + bv);
      }
    }
  }
}

// Flash-style MFMA attention (green in r14), reading the fused [8192][2048]
// buffer: q at +0, k at +512, v at +1024, u at +1536 (stride 2048).
#define SS 69
#define SP 72
#define QS 2048
__global__ __launch_bounds__(256) void attn_tile(
    const __bf16* __restrict__ qu,   // [B*L][2048]
    __bf16* __restrict__ g)          // [B*L][512]
{
  const int qt = blockIdx.x, h = blockIdx.y, b = blockIdx.z;
  const int t = threadIdx.x;
  const int lane = t & 63;
  const int w = t >> 6;
  const int q0 = qt * 64, qmax = q0 + 63;
  const size_t bL = (size_t)b * L_;

  __shared__ __bf16 lQ[4096];
  __shared__ __bf16 lK[4096];
  __shared__ __bf16 lV[64 * SP];
  __shared__ float  Ssh[64 * SS];
  __shared__ __bf16 Pb[64 * SP];
  __shared__ float  pmax[256], psum[256];
  __shared__ float  ms[64], lsum[64], corrs[64];

  {
    const int row = t >> 2, gb = t & 3;
    const __bf16* src = qu + (bL + q0 + row) * QS + h * 64;
    ((bf16x8*)lQ)[row * 8 + gb]     = *(const bf16x8*)(src + gb * 8);
    ((bf16x8*)lQ)[row * 8 + gb + 4] = *(const bf16x8*)(src + (gb + 4) * 8);
  }
  if (t < 64) { ms[t] = -1e30f; lsum[t] = 0.f; }

  int clist[5]; int ncl = 0;
  clist[ncl++] = 0;
  if (qmax >= 64) clist[ncl++] = 64;
  {
    int lo = 1921 - q0; if (lo < 0) lo = 0; lo &= ~63;
    const int hik = min(qmax, 2048 - q0);
    for (int c = lo; c <= hik; c += 64)
      if (c >= 128) clist[ncl++] = c;
  }

  f32x4 acc_o[4] = {};
  const int cq = lane >> 4, cc = lane & 15;

  for (int ci = 0; ci < ncl; ++ci) {
    const int c0 = clist[ci];
    __syncthreads();
    {
      const int row = t >> 2, gb = t & 3;
      const __bf16* src = qu + (bL + c0 + row) * QS + 512 + h * 64;
      ((bf16x8*)lK)[row * 8 + gb]     = *(const bf16x8*)(src + gb * 8);
      ((bf16x8*)lK)[row * 8 + gb + 4] = *(const bf16x8*)(src + (gb + 4) * 8);
    }
    {
      const int key = lane;
      const __bf16* src = qu + (bL + c0 + key) * QS + 1024 + h * 64 + w * 16;
      bf16x8 va = *(const bf16x8*)src;
      bf16x8 vb = *(const bf16x8*)(src + 8);
#pragma unroll
      for (int e = 0; e < 8; ++e) {
        lV[(w * 16 + e) * SP + key]     = va[e];
        lV[(w * 16 + 8 + e) * SP + key] = vb[e];
      }
    }
    __syncthreads();

    {
      const int r = cc, q = cq;
#pragma unroll
      for (int nt = 0; nt < 4; ++nt) {
        f32x4 s = {};
        bf16x8 aq0 = *(const bf16x8*)(lQ + (w * 16 + r) * 64 + q * 8);
        bf16x8 aq1 = *(const bf16x8*)(lQ + (w * 16 + r) * 64 + 32 + q * 8);
        bf16x8 bk0 = *(const bf16x8*)(lK + (nt * 16 + r) * 64 + q * 8);
        bf16x8 bk1 = *(const bf16x8*)(lK + (nt * 16 + r) * 64 + 32 + q * 8);
        s = __builtin_amdgcn_mfma_f32_16x16x32_bf16(aq0, bk0, s, 0, 0, 0);
        s = __builtin_amdgcn_mfma_f32_16x16x32_bf16(aq1, bk1, s, 0, 0, 0);
#pragma unroll
        for (int rr = 0; rr < 4; ++rr) {
          const int i = q0 + w * 16 + cq * 4 + rr;
          const int j = c0 + nt * 16 + cc;
          const int ij = i + j;
          const bool valid = (j <= i) &&
              ((ij >= 1984 && ij <= 2048) || (j <= 64 && ij <= 2048));
          Ssh[(w * 16 + cq * 4 + rr) * SS + nt * 16 + cc] =
              valid ? s[rr] * 0.125f : -1e30f;
        }
      }
    }
    __syncthreads();

    {
      float pm = -1e30f;
#pragma unroll
      for (int c = 0; c < 16; ++c) pm = fmaxf(pm, Ssh[lane * SS + w * 16 + c]);
      pmax[w * 64 + lane] = pm;
    }
    __syncthreads();
    if (t < 64) {
      float nm = ms[t];
#pragma unroll
      for (int q4 = 0; q4 < 4; ++q4) nm = fmaxf(nm, pmax[q4 * 64 + t]);
      corrs[t] = __expf(ms[t] - nm);
      ms[t] = nm;
    }
    __syncthreads();
    {
      const float nm = ms[lane];
      float ps = 0.f;
      bf16x8 p8a, p8b;
#pragma unroll
      for (int c = 0; c < 8; ++c) {
        const float p = __expf(Ssh[lane * SS + w * 16 + c] - nm);
        p8a[c] = (__bf16)p; ps += p;
      }
#pragma unroll
      for (int c = 0; c < 8; ++c) {
        const float p = __expf(Ssh[lane * SS + w * 16 + 8 + c] - nm);
        p8b[c] = (__bf16)p; ps += p;
      }
      *(bf16x8*)(Pb + lane * SP + w * 16)     = p8a;
      *(bf16x8*)(Pb + lane * SP + w * 16 + 8) = p8b;
      psum[w * 64 + lane] = ps;
    }
    __syncthreads();
    if (t < 64)
      lsum[t] = lsum[t] * corrs[t] + psum[t] + psum[64 + t] + psum[128 + t] + psum[192 + t];

    {
      const int r = cc, q = cq;
      float cr[4];
#pragma unroll
      for (int rr = 0; rr < 4; ++rr) cr[rr] = corrs[w * 16 + cq * 4 + rr];
#pragma unroll
      for (int dt = 0; dt < 4; ++dt) {
#pragma unroll
        for (int rr = 0; rr < 4; ++rr) acc_o[dt][rr] *= cr[rr];
        bf16x8 pa0 = *(const bf16x8*)(Pb + (w * 16 + r) * SP + q * 8);
        bf16x8 pa1 = *(const bf16x8*)(Pb + (w * 16 + r) * SP + 32 + q * 8);
        bf16x8 vb0 = *(const bf16x8*)(lV + (dt * 16 + r) * SP + q * 8);
        bf16x8 vb1 = *(const bf16x8*)(lV + (dt * 16 + r) * SP + 32 + q * 8);
        acc_o[dt] = __builtin_amdgcn_mfma_f32_16x16x32_bf16(pa0, vb0, acc_o[dt], 0, 0, 0);
        acc_o[dt] = __builtin_amdgcn_mfma_f32_16x16x32_bf16(pa1, vb1, acc_o[dt], 0, 0, 0);
      }
    }
  }
  __syncthreads();

#pragma unroll
  for (int dt = 0; dt < 4; ++dt) {
#pragma unroll
    for (int rr = 0; rr < 4; ++rr) {
      const int row16 = cq * 4 + rr;
      const size_t qrow = bL + q0 + w * 16 + row16;
      const int d = dt * 16 + cc;
      const float o = acc_o[dt][rr] / fmaxf(lsum[w * 16 + row16], 1e-30f);
      const float uv = (float)qu[qrow * QS + 1536 + h * 64 + d];
      g[qrow * D_ + h * 64 + d] = (__bf16)(o / (1.f + __expf(-o)) * uv);
    }
  }
}

extern "C" void kernel_launch(void* const* d_in, const int* in_sizes, int n_in,
                              void* d_out, int out_size, void* d_ws, size_t ws_size,
                              hipStream_t stream) {
  const float* x     = (const float*)d_in[0];
  const float* w_qkv = (const float*)d_in[1];
  const float* b_qkv = (const float*)d_in[2];
  const float* w_u   = (const float*)d_in[3];
  const float* b_u   = (const float*)d_in[4];
  const float* w_out = (const float*)d_in[5];
  const float* b_out = (const float*)d_in[6];
  float* out = (float*)d_out;

  char* ws = (char*)d_ws;
  __bf16* xb   = (__bf16*)ws;                           //  8 MB
  __bf16* wcat = (__bf16*)(ws + 8388608);               //  2 MB [w_qkv;w_u]
  __bf16* wob  = (__bf16*)(ws + 10485760);              //  0.5 MB
  float*  bcat = (float*) (ws + 11010048);              //  8 KB
  __bf16* qu   = (__bf16*)(ws + 11018240);              // 32 MB [q|k|v|u]
  __bf16* gb   = (__bf16*)(ws + 44572672);              //  8 MB

  cvt_pack<<<dim3(2688), dim3(256), 0, stream>>>(
      x, w_qkv, w_u, w_out, b_qkv, b_u, xb, wcat, wob, bcat);
  gemm_async<__bf16><<<dim3(64, 16), dim3(256), 0, stream>>>(
      xb, wcat, bcat, qu, 8192, 2048, 512);
  attn_tile<<<dim3(L_ / 64, H_, B_), dim3(256), 0, stream>>>(qu, gb);
  gemm_async<float><<<dim3(64, 4), dim3(256), 0, stream>>>(
      gb, wob, b_out, out, 8192, 512, 512);
}